// Round 1
// baseline (1004.967 us; speedup 1.0000x reference)
//
#include <hip/hip_runtime.h>
#include <hip/hip_bf16.h>
#include <stdint.h>

#define BATCH 16
#define CDIM  512
#define DDIM  512
#define NDIM  2048

#define TM 128
#define TN 128
#define BK 32
#define LP 40   // LDS pitch in bf16 elems (32 data + 8 pad)

using bf16x8 = __attribute__((ext_vector_type(8))) short;
using f32x4  = __attribute__((ext_vector_type(4))) float;

__device__ __forceinline__ unsigned short f2bf(float x) {
    union { float f; unsigned int u; } v; v.f = x;
    unsigned int r = v.u + 0x7FFFu + ((v.u >> 16) & 1u);   // RNE to bf16
    return (unsigned short)(r >> 16);
}
__device__ __forceinline__ float bf2f(unsigned short h) {
    union { unsigned int u; float f; } v; v.u = ((unsigned int)h) << 16;
    return v.f;
}
// order-preserving float<->uint key for atomicMax
__device__ __forceinline__ unsigned int fkey(float f) {
    union { float f; int i; } v; v.f = f;
    return (v.i >= 0) ? ((unsigned int)v.i | 0x80000000u) : (unsigned int)(~v.i);
}
__device__ __forceinline__ float funkey(unsigned int u) {
    union { unsigned int u; float f; } v;
    v.u = (u & 0x80000000u) ? (u & 0x7FFFFFFFu) : ~u;
    return v.f;
}

// ---- K_init: zero colmax keys (ws is poisoned 0xAA) ----
__global__ void init_colmax_k(unsigned int* __restrict__ colmax) {
    colmax[blockIdx.x * 256 + threadIdx.x] = 0u;
}

// ---- K0a: [b][c][n] fp32 -> transposed [b][n][c] bf16 hi/lo split ----
__global__ __launch_bounds__(256) void split_transpose_k(
    const float* __restrict__ in, unsigned short* __restrict__ hi,
    unsigned short* __restrict__ lo)
{
    __shared__ float tile[32][33];
    const int b  = blockIdx.z;
    const int n0 = blockIdx.x * 32;
    const int c0 = blockIdx.y * 32;
    const int t  = threadIdx.x;
    const int tn = t & 31, tc = t >> 5;           // load: 8 c-rows/pass
    const float* src = in + ((size_t)b * CDIM + c0) * NDIM + n0;
    #pragma unroll
    for (int i = 0; i < 4; ++i)
        tile[tc + 8 * i][tn] = src[(size_t)(tc + 8 * i) * NDIM + tn];
    __syncthreads();
    const int wn = t >> 5, wc = t & 31;           // store: c contiguous
    #pragma unroll
    for (int i = 0; i < 4; ++i) {
        const int n = wn + 8 * i;
        const float x = tile[wc][n];
        const unsigned short h = f2bf(x);
        const unsigned short l = f2bf(x - bf2f(h));
        const size_t o = ((size_t)b * NDIM + n0 + n) * CDIM + c0 + wc;
        hi[o] = h; lo[o] = l;
    }
}

// ---- K0b: fp32 -> bf16 elementwise (layout kept) ----
__global__ __launch_bounds__(256) void convert_bf16_k(
    const float* __restrict__ in, unsigned short* __restrict__ out)
{
    const size_t i = ((size_t)blockIdx.x * 256 + threadIdx.x) * 4;
    const float4 v = *(const float4*)(in + i);
    *(ushort4*)(out + i) = make_ushort4(f2bf(v.x), f2bf(v.y), f2bf(v.z), f2bf(v.w));
}

// ---- K1: scores = A1 * B1^T via split-bf16 (3 MFMA), + per-column max ----
__global__ __launch_bounds__(256, 2) void gemm1_k(
    const unsigned short* __restrict__ Ahi, const unsigned short* __restrict__ Alo,
    const unsigned short* __restrict__ Bhi, const unsigned short* __restrict__ Blo,
    float* __restrict__ scores, unsigned int* __restrict__ colmax)
{
    __shared__ unsigned short sA[2][TM * LP];
    __shared__ unsigned short sB[2][TN * LP];
    __shared__ unsigned int cmax_s[TN];

    const int t  = threadIdx.x;
    const int b  = blockIdx.z;
    const int m0 = blockIdx.y * TM;   // n2
    const int n0 = blockIdx.x * TN;   // n1
    if (t < TN) cmax_s[t] = 0u;

    const int srow = t >> 1;
    const int scol = (t & 1) * 16;
    const size_t aoff = ((size_t)b * NDIM + m0 + srow) * CDIM + scol;
    const size_t boff = ((size_t)b * NDIM + n0 + srow) * CDIM + scol;

    const int l  = t & 63;
    const int w  = t >> 6;
    const int wm = (w >> 1) * 64;
    const int wn = (w & 1) * 64;
    const int fm = l & 15;
    const int fq = l >> 4;

    f32x4 acc[4][4] = {};

    for (int k0 = 0; k0 < CDIM; k0 += BK) {
        __syncthreads();
        const int4 ah0 = *(const int4*)(Ahi + aoff + k0);
        const int4 ah1 = *(const int4*)(Ahi + aoff + k0 + 8);
        const int4 al0 = *(const int4*)(Alo + aoff + k0);
        const int4 al1 = *(const int4*)(Alo + aoff + k0 + 8);
        const int4 bh0 = *(const int4*)(Bhi + boff + k0);
        const int4 bh1 = *(const int4*)(Bhi + boff + k0 + 8);
        const int4 bl0 = *(const int4*)(Blo + boff + k0);
        const int4 bl1 = *(const int4*)(Blo + boff + k0 + 8);
        { int4* d = (int4*)&sA[0][srow * LP + scol]; d[0] = ah0; d[1] = ah1; }
        { int4* d = (int4*)&sA[1][srow * LP + scol]; d[0] = al0; d[1] = al1; }
        { int4* d = (int4*)&sB[0][srow * LP + scol]; d[0] = bh0; d[1] = bh1; }
        { int4* d = (int4*)&sB[1][srow * LP + scol]; d[0] = bl0; d[1] = bl1; }
        __syncthreads();

        bf16x8 a_h[4], a_l[4], b_h[4], b_l[4];
        #pragma unroll
        for (int f = 0; f < 4; ++f) {
            a_h[f] = *(const bf16x8*)&sA[0][(wm + f * 16 + fm) * LP + fq * 8];
            a_l[f] = *(const bf16x8*)&sA[1][(wm + f * 16 + fm) * LP + fq * 8];
            b_h[f] = *(const bf16x8*)&sB[0][(wn + f * 16 + fm) * LP + fq * 8];
            b_l[f] = *(const bf16x8*)&sB[1][(wn + f * 16 + fm) * LP + fq * 8];
        }
        #pragma unroll
        for (int fi = 0; fi < 4; ++fi)
            #pragma unroll
            for (int fj = 0; fj < 4; ++fj) {
                acc[fi][fj] = __builtin_amdgcn_mfma_f32_16x16x32_bf16(a_h[fi], b_h[fj], acc[fi][fj], 0, 0, 0);
                acc[fi][fj] = __builtin_amdgcn_mfma_f32_16x16x32_bf16(a_h[fi], b_l[fj], acc[fi][fj], 0, 0, 0);
                acc[fi][fj] = __builtin_amdgcn_mfma_f32_16x16x32_bf16(a_l[fi], b_h[fj], acc[fi][fj], 0, 0, 0);
            }
    }

    // per-column (n1) max, block-local then global
    #pragma unroll
    for (int fj = 0; fj < 4; ++fj) {
        float m = -3.4e38f;
        #pragma unroll
        for (int fi = 0; fi < 4; ++fi)
            #pragma unroll
            for (int r = 0; r < 4; ++r)
                m = fmaxf(m, acc[fi][fj][r]);
        atomicMax(&cmax_s[wn + fj * 16 + fm], fkey(m));
    }

    // write raw scores (C/D layout: row=fq*4+r, col=fm)
    #pragma unroll
    for (int fi = 0; fi < 4; ++fi)
        #pragma unroll
        for (int r = 0; r < 4; ++r) {
            const int row = wm + fi * 16 + fq * 4 + r;
            float* rp = scores + ((size_t)b * NDIM + m0 + row) * NDIM + n0 + wn;
            #pragma unroll
            for (int fj = 0; fj < 4; ++fj)
                rp[fj * 16 + fm] = acc[fi][fj][r];
        }

    __syncthreads();
    if (t < TN) atomicMax(&colmax[(size_t)b * NDIM + n0 + t], cmax_s[t]);
}

// ---- K2: per-column sum of exp(x - max) -> reciprocal ----
__global__ __launch_bounds__(256) void colsum_k(
    const float* __restrict__ scores, const unsigned int* __restrict__ colmax,
    float* __restrict__ colrcp)
{
    __shared__ float red[256];
    const int t   = threadIdx.x;
    const int b   = blockIdx.y;
    const int n0  = blockIdx.x * 64;
    const int col = t & 63, q = t >> 6;
    const float m = funkey(colmax[(size_t)b * NDIM + n0 + col]);
    const float* p = scores + ((size_t)b * NDIM + q * 512) * NDIM + n0 + col;
    float s = 0.f;
    #pragma unroll 4
    for (int r = 0; r < 512; ++r)
        s += __expf(p[(size_t)r * NDIM] - m);
    red[t] = s;
    __syncthreads();
    if (t < 64) {
        const float tot = red[t] + red[t + 64] + red[t + 128] + red[t + 192];
        colrcp[(size_t)b * NDIM + n0 + t] = 1.0f / tot;
    }
}

// ---- K3: normalize in place (fp32) + write bf16 transposed copy [b][n1][n2] ----
__global__ __launch_bounds__(256) void norm_transpose_k(
    float* __restrict__ attn, const unsigned int* __restrict__ colmax,
    const float* __restrict__ colrcp, unsigned short* __restrict__ attnT)
{
    __shared__ unsigned short tile[64][68];
    const int t   = threadIdx.x;
    const int b   = blockIdx.z;
    const int n20 = blockIdx.y * 64;
    const int n10 = blockIdx.x * 64;
    const int c4  = (t & 15) * 4;   // n1 within tile (float4)
    const int rr  = t >> 4;         // n2 row base
    const size_t cb = (size_t)b * NDIM + n10 + c4;
    const uint4  mu = *(const uint4*)(colmax + cb);
    const float4 rs = *(const float4*)(colrcp + cb);
    const float mx0 = funkey(mu.x), mx1 = funkey(mu.y), mx2 = funkey(mu.z), mx3 = funkey(mu.w);
    #pragma unroll
    for (int i = 0; i < 4; ++i) {
        const int n2 = rr + i * 16;
        float4* gp = (float4*)(attn + ((size_t)b * NDIM + n20 + n2) * NDIM + n10 + c4);
        float4 v = *gp;
        v.x = __expf(v.x - mx0) * rs.x;
        v.y = __expf(v.y - mx1) * rs.y;
        v.z = __expf(v.z - mx2) * rs.z;
        v.w = __expf(v.w - mx3) * rs.w;
        *gp = v;
        tile[n2][c4 + 0] = f2bf(v.x);
        tile[n2][c4 + 1] = f2bf(v.y);
        tile[n2][c4 + 2] = f2bf(v.z);
        tile[n2][c4 + 3] = f2bf(v.w);
    }
    __syncthreads();
    const int k4 = (t & 15) * 4;    // n2 group
    const int r1 = t >> 4;          // n1 row base
    #pragma unroll
    for (int i = 0; i < 4; ++i) {
        const int n1 = r1 + i * 16;
        const ushort4 o = make_ushort4(tile[k4 + 0][n1], tile[k4 + 1][n1],
                                       tile[k4 + 2][n1], tile[k4 + 3][n1]);
        *(ushort4*)(attnT + ((size_t)b * NDIM + n10 + n1) * NDIM + n20 + k4) = o;
    }
}

// ---- K4: RE_embed = RE2(bf16) * attnT(bf16), plain bf16 MFMA ----
__global__ __launch_bounds__(256, 2) void gemm2_k(
    const unsigned short* __restrict__ RE2bf, const unsigned short* __restrict__ attnT,
    float* __restrict__ out)
{
    __shared__ unsigned short sA[TM * LP];
    __shared__ unsigned short sB[TN * LP];
    const int t  = threadIdx.x;
    const int b  = blockIdx.z;
    const int d0 = blockIdx.y * TM;
    const int n0 = blockIdx.x * TN;
    const int srow = t >> 1;
    const int scol = (t & 1) * 16;
    const size_t aoff = ((size_t)b * DDIM + d0 + srow) * NDIM + scol;
    const size_t boff = ((size_t)b * NDIM + n0 + srow) * NDIM + scol;
    const int l  = t & 63;
    const int w  = t >> 6;
    const int wm = (w >> 1) * 64;
    const int wn = (w & 1) * 64;
    const int fm = l & 15;
    const int fq = l >> 4;

    f32x4 acc[4][4] = {};

    for (int k0 = 0; k0 < NDIM; k0 += BK) {
        __syncthreads();
        const int4 a0 = *(const int4*)(RE2bf + aoff + k0);
        const int4 a1 = *(const int4*)(RE2bf + aoff + k0 + 8);
        const int4 b0 = *(const int4*)(attnT + boff + k0);
        const int4 b1 = *(const int4*)(attnT + boff + k0 + 8);
        { int4* d = (int4*)&sA[srow * LP + scol]; d[0] = a0; d[1] = a1; }
        { int4* d = (int4*)&sB[srow * LP + scol]; d[0] = b0; d[1] = b1; }
        __syncthreads();
        bf16x8 af[4], bfr[4];
        #pragma unroll
        for (int f = 0; f < 4; ++f) {
            af[f]  = *(const bf16x8*)&sA[(wm + f * 16 + fm) * LP + fq * 8];
            bfr[f] = *(const bf16x8*)&sB[(wn + f * 16 + fm) * LP + fq * 8];
        }
        #pragma unroll
        for (int fi = 0; fi < 4; ++fi)
            #pragma unroll
            for (int fj = 0; fj < 4; ++fj)
                acc[fi][fj] = __builtin_amdgcn_mfma_f32_16x16x32_bf16(af[fi], bfr[fj], acc[fi][fj], 0, 0, 0);
    }

    #pragma unroll
    for (int fi = 0; fi < 4; ++fi)
        #pragma unroll
        for (int r = 0; r < 4; ++r) {
            const int row = wm + fi * 16 + fq * 4 + r;
            float* rp = out + ((size_t)b * DDIM + d0 + row) * NDIM + n0 + wn;
            #pragma unroll
            for (int fj = 0; fj < 4; ++fj)
                rp[fj * 16 + fm] = acc[fi][fj][r];
        }
}

extern "C" void kernel_launch(void* const* d_in, const int* in_sizes, int n_in,
                              void* d_out, int out_size, void* d_ws, size_t ws_size,
                              hipStream_t stream)
{
    const float* RI_1 = (const float*)d_in[0];
    const float* RI_2 = (const float*)d_in[1];
    const float* RE_2 = (const float*)d_in[2];

    float* out_embed = (float*)d_out;                         // [B][D][N1]
    float* attn = out_embed + (size_t)BATCH * DDIM * NDIM;    // [B][N2][N1]

    const size_t S = (size_t)BATCH * NDIM * CDIM;             // 16,777,216 elems
    unsigned short* A1hi  = (unsigned short*)d_ws;            // RI_2^T hi  [b][n2][c]
    unsigned short* A1lo  = A1hi + S;
    unsigned short* B1hi  = A1lo + S;                         // RI_1^T hi  [b][n1][c]
    unsigned short* B1lo  = B1hi + S;
    unsigned short* RE2bf = B1lo + S;                         // [b][d][n2]
    unsigned short* attnT = (unsigned short*)d_ws;            // [b][n1][n2] — reuses A1/B1 after gemm1
    unsigned int*   colmax = (unsigned int*)(RE2bf + S);
    float*          colrcp = (float*)(colmax + (size_t)BATCH * NDIM);

    const dim3 blk(256);
    init_colmax_k<<<dim3(BATCH * NDIM / 256), blk, 0, stream>>>(colmax);
    split_transpose_k<<<dim3(NDIM / 32, CDIM / 32, BATCH), blk, 0, stream>>>(RI_2, A1hi, A1lo);
    split_transpose_k<<<dim3(NDIM / 32, CDIM / 32, BATCH), blk, 0, stream>>>(RI_1, B1hi, B1lo);
    convert_bf16_k<<<dim3((BATCH * DDIM * NDIM) / 1024), blk, 0, stream>>>(RE_2, RE2bf);
    gemm1_k<<<dim3(NDIM / TN, NDIM / TM, BATCH), blk, 0, stream>>>(A1hi, A1lo, B1hi, B1lo, attn, colmax);
    colsum_k<<<dim3(NDIM / 64, BATCH), blk, 0, stream>>>(attn, colmax, colrcp);
    norm_transpose_k<<<dim3(NDIM / 64, NDIM / 64, BATCH), blk, 0, stream>>>(attn, colmax, colrcp, attnT);
    gemm2_k<<<dim3(NDIM / TN, DDIM / TM, BATCH), blk, 0, stream>>>(RE2bf, attnT, out_embed);
}